// Round 3
// baseline (2482.232 us; speedup 1.0000x reference)
//
#include <hip/hip_runtime.h>
#include <math.h>

#define N_TOK  16384
#define DIM    4096
#define NE     64
#define CAP    640
#define KC     16
#define TM     256
#define NTILES (N_TOK / TM)   // 64

// ws layout:
// [0,256):                     counts (64 int, zeroed per call)
// [256, 256+128K):             ws_idx   (int,   N*2)
// [256+128K, 256+256K):        ws_probs (float, N*2)
// [262400, ...):               partials (ks * N * 64 floats)

__device__ __forceinline__ void gl_lds16(const float* g, float* l) {
  // async global->LDS, 16B per lane; LDS dest is wave-uniform base + lane*16
  __builtin_amdgcn_global_load_lds((const __attribute__((address_space(1))) void*)g,
                                   (__attribute__((address_space(3))) void*)l, 16, 0, 0);
}

// LDS layout (per buffer): rows of 16 floats (64B), NO padding (gload_lds is linear).
//   slot (row, quad q) holds global quad q ^ key(row), key(row) = (row>>3)&3.
// Staging applies the XOR on the per-lane GLOBAL source address (linear LDS dest);
// reads apply the same XOR -> involution -> correct data, and the 8 rows a wave
// touches per read spread across quads as 2-way same-bank max (free, m136).
__global__ __launch_bounds__(256, 4) void gemm_logits_kernel(
    const float* __restrict__ x, const float* __restrict__ W,
    float* __restrict__ partials, int ks) {
  const int tile  = blockIdx.x % NTILES;
  const int split = blockIdx.x / NTILES;
  const int klen  = DIM / ks;
  const int k0    = split * klen;
  const int t_base = tile * TM;

  __shared__ float xs[2][KC * TM];  // 2 x 16 KB
  __shared__ float wss[2][KC * NE]; // 2 x  4 KB   (total 40 KB -> 4 blocks/CU exact)

  const int tid = threadIdx.x;
  const int tg  = tid >> 3;   // 0..31: token group of 8
  const int eg  = tid & 7;    // 0..7 : expert group of 8

  // staging lane mapping: 4 lanes per 64B row
  const int srow = tid >> 2;                        // 0..63
  const int sq   = (tid & 3) ^ ((tid >> 5) & 3);    // swizzled source quad

  const float* xg = x + (size_t)(t_base + srow) * DIM + k0 + 4 * sq;
  const float* wg = W + (size_t)srow * DIM + k0 + 4 * sq;
  float* xl = &xs[0][0]  + tid * 4;   // + buf*4096 + call*1024
  float* wl = &wss[0][0] + tid * 4;   // + buf*1024

  float acc[8][8];
#pragma unroll
  for (int i = 0; i < 8; ++i)
#pragma unroll
    for (int j = 0; j < 8; ++j) acc[i][j] = 0.f;

  const int niter = klen / KC;

  // prologue: stage tile 0 into buf 0 (x: 4 calls of 64 rows; w: 1 call)
  gl_lds16(xg,             xl);
  gl_lds16(xg +  64 * DIM, xl + 1024);
  gl_lds16(xg + 128 * DIM, xl + 2048);
  gl_lds16(xg + 192 * DIM, xl + 3072);
  gl_lds16(wg,             wl);
  __syncthreads();  // drains vmcnt: buf0 ready

  const int xkey = tg & 3;
  const int wkey = eg & 3;

  for (int it = 0; it < niter; ++it) {
    const int cur = it & 1;
    const int nxt = cur ^ 1;

    // issue next tile's async loads EARLY; they fly under the FMAs below
    if (it + 1 < niter) {
      const int ko = (it + 1) * KC;
      gl_lds16(xg + ko,             xl + nxt * 4096);
      gl_lds16(xg + ko +  64 * DIM, xl + nxt * 4096 + 1024);
      gl_lds16(xg + ko + 128 * DIM, xl + nxt * 4096 + 2048);
      gl_lds16(xg + ko + 192 * DIM, xl + nxt * 4096 + 3072);
      gl_lds16(wg + ko,             wl + nxt * 1024);
    }

    const float* xb = &xs[cur][0];
    const float* wb = &wss[cur][0];
#pragma unroll
    for (int kq = 0; kq < 4; ++kq) {
      const int xo = 4 * (kq ^ xkey);
      const int wo = 4 * (kq ^ wkey);
      float4 xa[8];
#pragma unroll
      for (int i = 0; i < 8; ++i)
        xa[i] = *(const float4*)(xb + (8 * tg + i) * 16 + xo);
#pragma unroll
      for (int j = 0; j < 8; ++j) {
        const float4 wv = *(const float4*)(wb + (8 * eg + j) * 16 + wo);
#pragma unroll
        for (int i = 0; i < 8; ++i) {
          acc[i][j] = fmaf(xa[i].x, wv.x, acc[i][j]);
          acc[i][j] = fmaf(xa[i].y, wv.y, acc[i][j]);
          acc[i][j] = fmaf(xa[i].z, wv.z, acc[i][j]);
          acc[i][j] = fmaf(xa[i].w, wv.w, acc[i][j]);
        }
      }
    }

    __syncthreads();  // all waves done reading buf[cur]; buf[nxt] loads drained
  }

  float* outp = partials + (size_t)split * N_TOK * NE;
#pragma unroll
  for (int i = 0; i < 8; ++i) {
    const int t = t_base + tg * 8 + i;
    const float4 v0 = make_float4(acc[i][0], acc[i][1], acc[i][2], acc[i][3]);
    const float4 v1 = make_float4(acc[i][4], acc[i][5], acc[i][6], acc[i][7]);
    *(float4*)(outp + (size_t)t * NE + eg * 8)     = v0;
    *(float4*)(outp + (size_t)t * NE + eg * 8 + 4) = v1;
  }
}

__global__ __launch_bounds__(64) void route_kernel(
    const float* __restrict__ partials, int ks,
    float* __restrict__ out, int* __restrict__ ws_idx,
    float* __restrict__ ws_probs, int* __restrict__ counts) {
  __shared__ int cnt[NE];
  const int tid = threadIdx.x;
  cnt[tid] = 0;  // blockDim == NE == 64
  __syncthreads();
  const int t = blockIdx.x * 64 + tid;

  // split-OUTER accumulation: per split the wave sweeps a dense 16 KB region
  float4 s[16];
  {
    const float* p = partials + (size_t)t * NE;
#pragma unroll
    for (int c = 0; c < 16; ++c) s[c] = *(const float4*)(p + 4 * c);
  }
  for (int sp = 1; sp < ks; ++sp) {
    const float* p = partials + (size_t)sp * N_TOK * NE + (size_t)t * NE;
#pragma unroll
    for (int c = 0; c < 16; ++c) {
      const float4 v = *(const float4*)(p + 4 * c);
      s[c].x += v.x; s[c].y += v.y; s[c].z += v.z; s[c].w += v.w;
    }
  }

  // top-2 with jax.lax.top_k tie semantics (lower index wins on equality)
  float b1 = -INFINITY, b2 = -INFINITY;
  int i1 = 0, i2 = 0;
#pragma unroll
  for (int c = 0; c < 16; ++c) {
    const float vv[4] = {s[c].x, s[c].y, s[c].z, s[c].w};
#pragma unroll
    for (int j = 0; j < 4; ++j) {
      const float v = vv[j];
      const int idx = c * 4 + j;
      if (v > b1)      { b2 = b1; i2 = i1; b1 = v; i1 = idx; }
      else if (v > b2) { b2 = v; i2 = idx; }
    }
  }
  const float ed = expf(b2 - b1);
  const float p1 = 1.0f / (1.0f + ed);
  const float p2 = ed / (1.0f + ed);

  out[(size_t)t * 2]     = p1;
  out[(size_t)t * 2 + 1] = p2;
  out[(size_t)N_TOK * 2 + t * 2]     = (float)i1;  // indices stored as f32
  out[(size_t)N_TOK * 2 + t * 2 + 1] = (float)i2;
  ws_idx[t * 2] = i1;  ws_idx[t * 2 + 1] = i2;
  ws_probs[t * 2] = p1; ws_probs[t * 2 + 1] = p2;

  atomicAdd(&cnt[i1], 1);
  atomicAdd(&cnt[i2], 1);
  __syncthreads();
  atomicAdd(&counts[tid], cnt[tid]);
}

__global__ __launch_bounds__(256) void capacity_kernel(
    const int* __restrict__ counts, const int* __restrict__ ws_idx,
    const float* __restrict__ ws_probs, float* __restrict__ out) {
  const int e = blockIdx.x;
  const int cnt = counts[e];
  if (threadIdx.x == 0) out[(size_t)N_TOK * 4 + e] = (float)cnt;
  if (cnt <= CAP) return;  // cold path: essentially never taken for this input
  for (int i = threadIdx.x; i < N_TOK * 2; i += 256) {
    if (ws_idx[i] != e) continue;
    const float p = ws_probs[i];
    const int tok = i >> 1;
    int rank = 0;
    for (int j = 0; j < N_TOK * 2; ++j) {
      if (ws_idx[j] != e) continue;
      const float q = ws_probs[j];
      if (q > p || (q == p && (j >> 1) < tok)) ++rank;
    }
    if (rank >= CAP) {
      out[i] = 0.0f;                                   // dropped prob
      out[(size_t)N_TOK * 2 + i] = 2147483648.0f;      // INT32_MAX as f32
    }
  }
}

extern "C" void kernel_launch(void* const* d_in, const int* in_sizes, int n_in,
                              void* d_out, int out_size, void* d_ws, size_t ws_size,
                              hipStream_t stream) {
  const float* x = (const float*)d_in[0];
  const float* W = (const float*)d_in[1];
  float* out = (float*)d_out;

  char* ws = (char*)d_ws;
  int*   counts   = (int*)ws;
  int*   ws_idx   = (int*)(ws + 256);
  float* ws_probs = (float*)(ws + 256 + (size_t)N_TOK * 2 * 4);
  float* partials = (float*)(ws + 262400);

  const size_t base = 262400;
  const size_t per  = (size_t)N_TOK * NE * 4;  // 4 MB per K-split partial
  int ks = 1;
  if (ws_size >= base + 16 * per)     ks = 16;  // 1024 blocks = 4/CU exact (40 KB LDS)
  else if (ws_size >= base + 8 * per) ks = 8;   //  512 blocks = 2/CU exact
  else if (ws_size >= base + 4 * per) ks = 4;   //  256 blocks = 1/CU exact
  else if (ws_size >= base + 2 * per) ks = 2;

  hipMemsetAsync(counts, 0, NE * sizeof(int), stream);
  gemm_logits_kernel<<<NTILES * ks, 256, 0, stream>>>(x, W, partials, ks);
  route_kernel<<<N_TOK / 64, 64, 0, stream>>>(partials, ks, out, ws_idx, ws_probs, counts);
  capacity_kernel<<<NE, 256, 0, stream>>>(counts, ws_idx, ws_probs, out);
}

// Round 4
// 437.120 us; speedup vs baseline: 5.6786x; 5.6786x over previous
//
#include <hip/hip_runtime.h>
#include <math.h>

#define N_TOK  16384
#define DIM    4096
#define NE     64
#define CAP    640
#define KC     32
#define TM     128
#define NTILES (N_TOK / TM)   // 128

// ws layout:
// [0,256):                     counts (64 int, zeroed per call)
// [256, 256+128K):             ws_idx   (int,   N*2)
// [256+128K, 256+256K):        ws_probs (float, N*2)
// [262400, 262400+1M):         Wt (transposed gate weights, [DIM][NE] f32)
// [1310976, ...):              partials (ks * N * 64 floats)

__device__ __forceinline__ void gl_lds16(const float* g, float* l) {
  // async global->LDS, 16B per lane; LDS dest is wave-uniform base + lane*16
  __builtin_amdgcn_global_load_lds((const __attribute__((address_space(1))) void*)g,
                                   (__attribute__((address_space(3))) void*)l, 16, 0, 0);
}

__global__ __launch_bounds__(256) void wt_kernel(
    const float* __restrict__ W, float* __restrict__ Wt) {
  // Wt[k][e] = W[e][k]; strided reads are L2-absorbed (W is 1 MB), writes coalesced
  const int idx = blockIdx.x * 256 + threadIdx.x;   // 0 .. DIM*NE
  const int k = idx >> 6, e = idx & 63;
  Wt[idx] = W[(size_t)e * DIM + k];
}

// x LDS layout (per buffer): rows of 32 floats (128B, full bank span), NO padding.
//   slot (row, quad q) holds global quad q ^ (row & 7)  (XOR applied on the
//   per-lane GLOBAL source address; LDS dest stays linear for gload_lds).
// Reads at quad kq ^ (row&7) retrieve global quad kq -> involution correct.
// W never touches LDS: each wave owns 16 experts (wave-uniform via
// readfirstlane), so W values load as s_load_dwordx16 from Wt[k][e] and feed
// v_fma as the (single allowed) SGPR operand. This removes 2/3 of the round-2
// LDS-pipe load, which was the binding pipe (123us vs 55us FMA).
__global__ __launch_bounds__(256, 2) void gemm_logits_kernel(
    const float* __restrict__ x, const float* __restrict__ Wt,
    float* __restrict__ partials, int ks) {
  const int tile  = blockIdx.x % NTILES;
  const int split = blockIdx.x / NTILES;
  const int klen  = DIM / ks;
  const int k0    = split * klen;
  const int t_base = tile * TM;

  __shared__ float xs[2][KC * TM];  // 2 x 16 KB = 32 KB -> 4+ blocks/CU

  const int tid  = threadIdx.x;
  const int tg   = tid >> 3;        // staging row group 0..31
  const int lk   = tid & 7;         // staging quad 0..7
  const int lane = tid & 63;
  const int lkey = lane & 7;
  const int wv   = __builtin_amdgcn_readfirstlane(tid >> 6);  // wave id 0..3

  const int klx = 4 * (lk ^ (tg & 7));   // swizzled global source quad
  const float* xg = x + (size_t)(t_base + tg) * DIM + k0 + klx;
  float* xl = &xs[0][0] + tid * 4;       // + buf*4096 + call*1024

  // wave-uniform W pointer: 16 experts [16*wv, 16*wv+16), k-major rows of 64
  const float* wtw = Wt + (size_t)k0 * NE + wv * 16;

  float acc0[16], acc1[16];
#pragma unroll
  for (int e = 0; e < 16; ++e) { acc0[e] = 0.f; acc1[e] = 0.f; }

  const int niter = klen / KC;

  // prologue: stage x tile 0 into buf 0 (4 calls of 32 rows)
  gl_lds16(xg,            xl);
  gl_lds16(xg + 32 * DIM, xl + 1024);
  gl_lds16(xg + 64 * DIM, xl + 2048);
  gl_lds16(xg + 96 * DIM, xl + 3072);
  __syncthreads();  // drains vmcnt: buf0 ready

  for (int it = 0; it < niter; ++it) {
    const int cur = it & 1;
    const int nxt = cur ^ 1;

    // issue next x tile's async loads EARLY; they fly under the FMAs below
    if (it + 1 < niter) {
      const int ko = (it + 1) * KC;
      gl_lds16(xg + ko,            xl + nxt * 4096);
      gl_lds16(xg + ko + 32 * DIM, xl + nxt * 4096 + 1024);
      gl_lds16(xg + ko + 64 * DIM, xl + nxt * 4096 + 2048);
      gl_lds16(xg + ko + 96 * DIM, xl + nxt * 4096 + 3072);
    }

    const float* xb  = &xs[cur][0];
    const float* wtt = wtw + (size_t)it * KC * NE;  // uniform
#pragma unroll
    for (int kq = 0; kq < 8; ++kq) {
      const int xo = 4 * (kq ^ lkey);
      const float4 xa0 = *(const float4*)(xb + lane * 32 + xo);          // token t_base+lane
      const float4 xa1 = *(const float4*)(xb + (lane + 64) * 32 + xo);   // token t_base+lane+64
      const float x0[4] = {xa0.x, xa0.y, xa0.z, xa0.w};
      const float x1[4] = {xa1.x, xa1.y, xa1.z, xa1.w};
#pragma unroll
      for (int j = 0; j < 4; ++j) {
        const float* wk = wtt + (kq * 4 + j) * NE;  // uniform: 16 consecutive floats
#pragma unroll
        for (int e = 0; e < 16; ++e) {
          const float w = wk[e];                    // SGPR operand
          acc0[e] = fmaf(x0[j], w, acc0[e]);
          acc1[e] = fmaf(x1[j], w, acc1[e]);
        }
      }
    }

    __syncthreads();  // all waves done with buf[cur]; buf[nxt] loads drained
  }

  float* outp = partials + (size_t)split * N_TOK * NE;
  const int t0 = t_base + lane;
  const int t1 = t0 + 64;
#pragma unroll
  for (int q = 0; q < 4; ++q) {
    *(float4*)(outp + (size_t)t0 * NE + wv * 16 + 4 * q) =
        make_float4(acc0[4 * q], acc0[4 * q + 1], acc0[4 * q + 2], acc0[4 * q + 3]);
    *(float4*)(outp + (size_t)t1 * NE + wv * 16 + 4 * q) =
        make_float4(acc1[4 * q], acc1[4 * q + 1], acc1[4 * q + 2], acc1[4 * q + 3]);
  }
}

__global__ __launch_bounds__(64) void route_kernel(
    const float* __restrict__ partials, int ks,
    float* __restrict__ out, int* __restrict__ ws_idx,
    float* __restrict__ ws_probs, int* __restrict__ counts) {
  __shared__ int cnt[NE];
  const int tid = threadIdx.x;
  cnt[tid] = 0;  // blockDim == NE == 64
  __syncthreads();
  const int t = blockIdx.x * 64 + tid;

  // split-OUTER accumulation: per split the wave sweeps a dense 16 KB region
  float4 s[16];
  {
    const float* p = partials + (size_t)t * NE;
#pragma unroll
    for (int c = 0; c < 16; ++c) s[c] = *(const float4*)(p + 4 * c);
  }
  for (int sp = 1; sp < ks; ++sp) {
    const float* p = partials + (size_t)sp * N_TOK * NE + (size_t)t * NE;
#pragma unroll
    for (int c = 0; c < 16; ++c) {
      const float4 v = *(const float4*)(p + 4 * c);
      s[c].x += v.x; s[c].y += v.y; s[c].z += v.z; s[c].w += v.w;
    }
  }

  // top-2 with jax.lax.top_k tie semantics (lower index wins on equality)
  float b1 = -INFINITY, b2 = -INFINITY;
  int i1 = 0, i2 = 0;
#pragma unroll
  for (int c = 0; c < 16; ++c) {
    const float vv[4] = {s[c].x, s[c].y, s[c].z, s[c].w};
#pragma unroll
    for (int j = 0; j < 4; ++j) {
      const float v = vv[j];
      const int idx = c * 4 + j;
      if (v > b1)      { b2 = b1; i2 = i1; b1 = v; i1 = idx; }
      else if (v > b2) { b2 = v; i2 = idx; }
    }
  }
  const float ed = expf(b2 - b1);
  const float p1 = 1.0f / (1.0f + ed);
  const float p2 = ed / (1.0f + ed);

  out[(size_t)t * 2]     = p1;
  out[(size_t)t * 2 + 1] = p2;
  out[(size_t)N_TOK * 2 + t * 2]     = (float)i1;  // indices stored as f32
  out[(size_t)N_TOK * 2 + t * 2 + 1] = (float)i2;
  ws_idx[t * 2] = i1;  ws_idx[t * 2 + 1] = i2;
  ws_probs[t * 2] = p1; ws_probs[t * 2 + 1] = p2;

  atomicAdd(&cnt[i1], 1);
  atomicAdd(&cnt[i2], 1);
  __syncthreads();
  atomicAdd(&counts[tid], cnt[tid]);
}

__global__ __launch_bounds__(256) void capacity_kernel(
    const int* __restrict__ counts, const int* __restrict__ ws_idx,
    const float* __restrict__ ws_probs, float* __restrict__ out) {
  const int e = blockIdx.x;
  const int cnt = counts[e];
  if (threadIdx.x == 0) out[(size_t)N_TOK * 4 + e] = (float)cnt;
  if (cnt <= CAP) return;  // cold path: essentially never taken for this input
  for (int i = threadIdx.x; i < N_TOK * 2; i += 256) {
    if (ws_idx[i] != e) continue;
    const float p = ws_probs[i];
    const int tok = i >> 1;
    int rank = 0;
    for (int j = 0; j < N_TOK * 2; ++j) {
      if (ws_idx[j] != e) continue;
      const float q = ws_probs[j];
      if (q > p || (q == p && (j >> 1) < tok)) ++rank;
    }
    if (rank >= CAP) {
      out[i] = 0.0f;                                   // dropped prob
      out[(size_t)N_TOK * 2 + i] = 2147483648.0f;      // INT32_MAX as f32
    }
  }
}

extern "C" void kernel_launch(void* const* d_in, const int* in_sizes, int n_in,
                              void* d_out, int out_size, void* d_ws, size_t ws_size,
                              hipStream_t stream) {
  const float* x = (const float*)d_in[0];
  const float* W = (const float*)d_in[1];
  float* out = (float*)d_out;

  char* ws = (char*)d_ws;
  int*   counts   = (int*)ws;
  int*   ws_idx   = (int*)(ws + 256);
  float* ws_probs = (float*)(ws + 256 + (size_t)N_TOK * 2 * 4);
  float* Wt       = (float*)(ws + 262400);
  float* partials = (float*)(ws + 262400 + (size_t)DIM * NE * 4);  // 1310976

  const size_t base = 262400 + (size_t)DIM * NE * 4;
  const size_t per  = (size_t)N_TOK * NE * 4;  // 4 MB per K-split partial
  int ks = 1;
  if (ws_size >= base + 8 * per)      ks = 8;  // 1024 blocks = 4/CU co-resident, no tail
  else if (ws_size >= base + 4 * per) ks = 4;
  else if (ws_size >= base + 2 * per) ks = 2;

  hipMemsetAsync(counts, 0, NE * sizeof(int), stream);
  wt_kernel<<<DIM * NE / 256, 256, 0, stream>>>(W, Wt);
  gemm_logits_kernel<<<NTILES * ks, 256, 0, stream>>>(x, Wt, partials, ks);
  route_kernel<<<N_TOK / 64, 64, 0, stream>>>(partials, ks, out, ws_idx, ws_probs, counts);
  capacity_kernel<<<NE, 256, 0, stream>>>(counts, ws_idx, ws_probs, out);
}

// Round 5
// 437.065 us; speedup vs baseline: 5.6793x; 1.0001x over previous
//
#include <hip/hip_runtime.h>
#include <math.h>

#define N_TOK  16384
#define DIM    4096
#define NE     64
#define CAP    640
#define KC     32
#define TM     256
#define NTILES (N_TOK / TM)   // 64

// ws layout:
// [0,256):                     counts (64 int, zeroed per call)
// [256, 256+128K):             ws_idx   (int,   N*2)
// [256+128K, 256+256K):        ws_probs (float, N*2)
// [262400, ...):               partials (ks * N * 64 floats)

__device__ __forceinline__ void gl_lds16(const float* g, float* l) {
  // async global->LDS, 16B per lane; LDS dest is wave-uniform base + lane*16
  __builtin_amdgcn_global_load_lds((const __attribute__((address_space(1))) void*)g,
                                   (__attribute__((address_space(3))) void*)l, 16, 0, 0);
}

// LDS layout (both x and W): rows of 32 floats (128B = full bank span), linear
// (gload_lds requirement). Slot (row, quad q) holds global quad q ^ key(row),
// key(row) = (row>>3)&7, applied on the per-lane GLOBAL source address at
// staging and re-applied at read (involution). Read groups: 8 distinct rows
// per wave per instr (8-lane broadcast each), keys distinct -> 8 distinct
// bank quads -> conflict-free (this exact scheme measured 0 conflicts in R2).
//
// Blocking: block = 256 thr = 4 waves, tile 256 tok x 64 exp. Lane = (tg,eg),
// tg=tid>>3 in 0..31, eg=tid&7; lane computes 8 tokens x 8 experts (acc 64).
// Per kq: 8 W-quad reads (held in regs, reused over 8 tokens) + 8 x reads
// -> 128 ds_read_b128 per wave-tile for 2048 FMAs (2x fewer reads/FMA than
// R2's 96/1024, which was the binding pipe at 123us; model now ~82us).
// R3's 8x8 failure was the (256,4) VGPR cap (spill); here (256,2) caps 128,
// need ~115. LDS 80KB -> 2 blocks/CU, grid 512 @ks=8 -> co-resident, no tail.
__global__ __launch_bounds__(256, 2) void gemm_logits_kernel(
    const float* __restrict__ x, const float* __restrict__ W,
    float* __restrict__ partials, int ks) {
  const int tile  = blockIdx.x % NTILES;
  const int split = blockIdx.x / NTILES;
  const int klen  = DIM / ks;
  const int k0    = split * klen;
  const int t_base = tile * TM;

  __shared__ float xs[2][KC * TM];  // 2 x 32 KB
  __shared__ float wss[2][KC * NE]; // 2 x  8 KB   (total 80 KB -> 2 blocks/CU)

  const int tid  = threadIdx.x;
  const int tg   = tid >> 3;   // 0..31: token group (8 tokens each)
  const int eg   = tid & 7;    // 0..7 : expert group (8 experts each)

  // staging lane mapping: 8 lanes per 128B row, 32 rows per gload_lds call
  const int srow = tid >> 3;   // 0..31
  const int lk   = tid & 7;    // quad slot within row
  const int sk   = srow >> 3;  // 0..3: key of row srow (even calls); odd calls key^4

  const float* xgE = x + (size_t)(t_base + srow) * DIM + k0 + 4 * (lk ^ sk);
  const float* xgO = x + (size_t)(t_base + srow) * DIM + k0 + 4 * (lk ^ sk ^ 4);
  const float* wgE = W + (size_t)srow * DIM + k0 + 4 * (lk ^ sk);
  const float* wgO = W + (size_t)(srow + 32) * DIM + k0 + 4 * (lk ^ sk ^ 4);
  float* xl = &xs[0][0]  + tid * 4;
  float* wl = &wss[0][0] + tid * 4;

#define STAGE(b, ko)                                              \
  do {                                                            \
    gl_lds16(xgE + (ko),             xl + (b) * 8192);            \
    gl_lds16(xgO + (ko) +  32 * DIM, xl + (b) * 8192 + 1024);     \
    gl_lds16(xgE + (ko) +  64 * DIM, xl + (b) * 8192 + 2048);     \
    gl_lds16(xgO + (ko) +  96 * DIM, xl + (b) * 8192 + 3072);     \
    gl_lds16(xgE + (ko) + 128 * DIM, xl + (b) * 8192 + 4096);     \
    gl_lds16(xgO + (ko) + 160 * DIM, xl + (b) * 8192 + 5120);     \
    gl_lds16(xgE + (ko) + 192 * DIM, xl + (b) * 8192 + 6144);     \
    gl_lds16(xgO + (ko) + 224 * DIM, xl + (b) * 8192 + 7168);     \
    gl_lds16(wgE + (ko),             wl + (b) * 2048);            \
    gl_lds16(wgO + (ko),             wl + (b) * 2048 + 1024);     \
  } while (0)

  float acc[8][8];
#pragma unroll
  for (int i = 0; i < 8; ++i)
#pragma unroll
    for (int j = 0; j < 8; ++j) acc[i][j] = 0.f;

  const int niter = klen / KC;
  const int xkey  = tg & 7;

  STAGE(0, 0);
  __syncthreads();  // vmcnt drained before barrier: buf0 ready

  for (int it = 0; it < niter; ++it) {
    const int cur = it & 1;
    const int nxt = cur ^ 1;

    // issue next tile's async loads EARLY; they fly under the FMAs below and
    // are drained by the vmcnt(0) the compiler emits before the end barrier
    if (it + 1 < niter) STAGE(nxt, (it + 1) * KC);

    const float* xb = &xs[cur][0];
    const float* wb = &wss[cur][0];
#pragma unroll
    for (int kq = 0; kq < 8; ++kq) {
      // W quads for this kq: 8 experts, held in regs, reused across 8 tokens
      float4 wv[8];
#pragma unroll
      for (int j = 0; j < 8; ++j)
        wv[j] = *(const float4*)(wb + (8 * eg + j) * 32 + 4 * (kq ^ eg));
#pragma unroll
      for (int i = 0; i < 8; ++i) {
        const float4 xv = *(const float4*)(xb + (tg * 8 + i) * 32 + 4 * (kq ^ xkey));
#pragma unroll
        for (int j = 0; j < 8; ++j) {
          acc[i][j] = fmaf(xv.x, wv[j].x, acc[i][j]);
          acc[i][j] = fmaf(xv.y, wv[j].y, acc[i][j]);
          acc[i][j] = fmaf(xv.z, wv[j].z, acc[i][j]);
          acc[i][j] = fmaf(xv.w, wv[j].w, acc[i][j]);
        }
      }
    }

    __syncthreads();  // all waves done reading buf[cur]; buf[nxt] loads drained
  }
#undef STAGE

  float* outp = partials + (size_t)split * N_TOK * NE;
#pragma unroll
  for (int i = 0; i < 8; ++i) {
    const int t = t_base + tg * 8 + i;
    const float4 v0 = make_float4(acc[i][0], acc[i][1], acc[i][2], acc[i][3]);
    const float4 v1 = make_float4(acc[i][4], acc[i][5], acc[i][6], acc[i][7]);
    *(float4*)(outp + (size_t)t * NE + eg * 8)     = v0;
    *(float4*)(outp + (size_t)t * NE + eg * 8 + 4) = v1;
  }
}

__global__ __launch_bounds__(64) void route_kernel(
    const float* __restrict__ partials, int ks,
    float* __restrict__ out, int* __restrict__ ws_idx,
    float* __restrict__ ws_probs, int* __restrict__ counts) {
  __shared__ int cnt[NE];
  const int tid = threadIdx.x;
  cnt[tid] = 0;  // blockDim == NE == 64
  __syncthreads();
  const int t = blockIdx.x * 64 + tid;

  // split-OUTER accumulation: per split the wave sweeps a dense 16 KB region
  float4 s[16];
  {
    const float* p = partials + (size_t)t * NE;
#pragma unroll
    for (int c = 0; c < 16; ++c) s[c] = *(const float4*)(p + 4 * c);
  }
  for (int sp = 1; sp < ks; ++sp) {
    const float* p = partials + (size_t)sp * N_TOK * NE + (size_t)t * NE;
#pragma unroll
    for (int c = 0; c < 16; ++c) {
      const float4 v = *(const float4*)(p + 4 * c);
      s[c].x += v.x; s[c].y += v.y; s[c].z += v.z; s[c].w += v.w;
    }
  }

  // top-2 with jax.lax.top_k tie semantics (lower index wins on equality)
  float b1 = -INFINITY, b2 = -INFINITY;
  int i1 = 0, i2 = 0;
#pragma unroll
  for (int c = 0; c < 16; ++c) {
    const float vv[4] = {s[c].x, s[c].y, s[c].z, s[c].w};
#pragma unroll
    for (int j = 0; j < 4; ++j) {
      const float v = vv[j];
      const int idx = c * 4 + j;
      if (v > b1)      { b2 = b1; i2 = i1; b1 = v; i1 = idx; }
      else if (v > b2) { b2 = v; i2 = idx; }
    }
  }
  const float ed = expf(b2 - b1);
  const float p1 = 1.0f / (1.0f + ed);
  const float p2 = ed / (1.0f + ed);

  out[(size_t)t * 2]     = p1;
  out[(size_t)t * 2 + 1] = p2;
  out[(size_t)N_TOK * 2 + t * 2]     = (float)i1;  // indices stored as f32
  out[(size_t)N_TOK * 2 + t * 2 + 1] = (float)i2;
  ws_idx[t * 2] = i1;  ws_idx[t * 2 + 1] = i2;
  ws_probs[t * 2] = p1; ws_probs[t * 2 + 1] = p2;

  atomicAdd(&cnt[i1], 1);
  atomicAdd(&cnt[i2], 1);
  __syncthreads();
  atomicAdd(&counts[tid], cnt[tid]);
}

__global__ __launch_bounds__(256) void capacity_kernel(
    const int* __restrict__ counts, const int* __restrict__ ws_idx,
    const float* __restrict__ ws_probs, float* __restrict__ out) {
  const int e = blockIdx.x;
  const int cnt = counts[e];
  if (threadIdx.x == 0) out[(size_t)N_TOK * 4 + e] = (float)cnt;
  if (cnt <= CAP) return;  // cold path: essentially never taken for this input
  for (int i = threadIdx.x; i < N_TOK * 2; i += 256) {
    if (ws_idx[i] != e) continue;
    const float p = ws_probs[i];
    const int tok = i >> 1;
    int rank = 0;
    for (int j = 0; j < N_TOK * 2; ++j) {
      if (ws_idx[j] != e) continue;
      const float q = ws_probs[j];
      if (q > p || (q == p && (j >> 1) < tok)) ++rank;
    }
    if (rank >= CAP) {
      out[i] = 0.0f;                                   // dropped prob
      out[(size_t)N_TOK * 2 + i] = 2147483648.0f;      // INT32_MAX as f32
    }
  }
}

extern "C" void kernel_launch(void* const* d_in, const int* in_sizes, int n_in,
                              void* d_out, int out_size, void* d_ws, size_t ws_size,
                              hipStream_t stream) {
  const float* x = (const float*)d_in[0];
  const float* W = (const float*)d_in[1];
  float* out = (float*)d_out;

  char* ws = (char*)d_ws;
  int*   counts   = (int*)ws;
  int*   ws_idx   = (int*)(ws + 256);
  float* ws_probs = (float*)(ws + 256 + (size_t)N_TOK * 2 * 4);
  float* partials = (float*)(ws + 262400);

  const size_t base = 262400;
  const size_t per  = (size_t)N_TOK * NE * 4;  // 4 MB per K-split partial
  int ks = 1;
  if (ws_size >= base + 8 * per)      ks = 8;  // 512 blocks = 2/CU co-resident, no tail
  else if (ws_size >= base + 4 * per) ks = 4;  // 256 blocks = 1/CU
  else if (ws_size >= base + 2 * per) ks = 2;

  hipMemsetAsync(counts, 0, NE * sizeof(int), stream);
  gemm_logits_kernel<<<NTILES * ks, 256, 0, stream>>>(x, W, partials, ks);
  route_kernel<<<N_TOK / 64, 64, 0, stream>>>(partials, ks, out, ws_idx, ws_probs, counts);
  capacity_kernel<<<NE, 256, 0, stream>>>(counts, ws_idx, ws_probs, out);
}